// Round 1
// baseline (402.971 us; speedup 1.0000x reference)
//
#include <hip/hip_runtime.h>
#include <math.h>

// One wave (64 lanes) per output row. D = 512 floats = 128 float4 per row;
// each lane owns float4 #lane and #(lane+64): 2 coalesced 1 KiB loads + 2 stores.
__global__ __launch_bounds__(256) void hstu_gather_norm_kernel(
    const float* __restrict__ values,
    const int* __restrict__ so,       // seqlen_offsets        (B+1)
    const int* __restrict__ nc,       // num_candidates_offsets (B+1)
    float* __restrict__ out,          // (total, D)
    int B, int total)
{
    const int D = 512;
    int row = blockIdx.x * 4 + (threadIdx.x >> 6);
    if (row >= total) return;
    int lane = threadIdx.x & 63;

    // seg = searchsorted(nc[1:], row, 'right')  ==  largest j in [0,B] with nc[j] <= row
    int lo = 0, hi = B;
    while (lo < hi) {
        int mid = (lo + hi + 1) >> 1;
        if (nc[mid] <= row) lo = mid; else hi = mid - 1;
    }
    int seg = lo;
    int pos = row - nc[seg];
    // len_a[seg] = diff(so - nc)[seg]
    int len_a = (so[seg + 1] - nc[seg + 1]) - (so[seg] - nc[seg]);
    long src = (long)so[seg] + (long)len_a + (long)pos;

    const float4* __restrict__ vr = (const float4*)(values + src * (long)D);
    float4 a = vr[lane];
    float4 b = vr[lane + 64];

    float ss = a.x * a.x + a.y * a.y + a.z * a.z + a.w * a.w
             + b.x * b.x + b.y * b.y + b.z * b.z + b.w * b.w;

    // 64-lane butterfly reduction
    #pragma unroll
    for (int off = 32; off > 0; off >>= 1)
        ss += __shfl_xor(ss, off, 64);

    float norm = sqrtf(ss);
    float scale = 1.0f / fmaxf(norm, 1e-6f);

    a.x *= scale; a.y *= scale; a.z *= scale; a.w *= scale;
    b.x *= scale; b.y *= scale; b.z *= scale; b.w *= scale;

    float4* __restrict__ orow = (float4*)(out + (long)row * D);
    orow[lane]      = a;
    orow[lane + 64] = b;
}

// Small outputs: seqlen = diff(nc) (B elems), then nc passthrough (B+1 elems),
// written as float32 (the flat output buffer is fp32; values <= 32768 are exact).
__global__ void hstu_tail_kernel(const int* __restrict__ nc,
                                 float* __restrict__ out_seqlen,
                                 float* __restrict__ out_off,
                                 int B)
{
    int i = blockIdx.x * blockDim.x + threadIdx.x;
    if (i < B)  out_seqlen[i] = (float)(nc[i + 1] - nc[i]);
    if (i <= B) out_off[i]    = (float)nc[i];
}

extern "C" void kernel_launch(void* const* d_in, const int* in_sizes, int n_in,
                              void* d_out, int out_size, void* d_ws, size_t ws_size,
                              hipStream_t stream) {
    const float* values = (const float*)d_in[0];
    const int*   so     = (const int*)d_in[1];   // seqlen_offsets
    const int*   nc     = (const int*)d_in[2];   // num_candidates_offsets
    // d_in[3] = total_candidates scalar (device); derive host-side instead.

    const int D = 512;
    int B = in_sizes[1] - 1;                         // 128
    int total = (out_size - (2 * B + 1)) / D;        // 32768

    float* out        = (float*)d_out;
    float* out_seqlen = out + (long)total * D;
    float* out_off    = out_seqlen + B;

    int grid = (total + 3) / 4;                      // 4 rows (waves) per 256-thread block
    hstu_gather_norm_kernel<<<grid, 256, 0, stream>>>(values, so, nc, out, B, total);
    hstu_tail_kernel<<<1, 256, 0, stream>>>(nc, out_seqlen, out_off, B);
}

// Round 2
// 401.231 us; speedup vs baseline: 1.0043x; 1.0043x over previous
//
#include <hip/hip_runtime.h>
#include <math.h>

// One wave (64 lanes) per output row. D = 512 floats = 128 float4 per row;
// each lane owns float4 #lane and #(lane+64): 2 coalesced 1 KiB loads + 2 stores.
// The last block (blockIdx == rowBlocks) writes the two small int outputs
// (as float — the flat output buffer is fp32; values <= 32768 are exact),
// saving a second kernel launch / graph node.
__global__ __launch_bounds__(256) void hstu_gather_norm_kernel(
    const float* __restrict__ values,
    const int* __restrict__ so,       // seqlen_offsets         (B+1)
    const int* __restrict__ nc,       // num_candidates_offsets (B+1)
    float* __restrict__ out,          // (total, D) then seqlen(B), nc(B+1)
    int B, int total, int rowBlocks)
{
    const int D = 512;

    if (blockIdx.x == rowBlocks) {
        // tail: seqlen = diff(nc), then nc passthrough
        float* out_seqlen = out + (long)total * D;
        float* out_off    = out_seqlen + B;
        for (int i = threadIdx.x; i <= B; i += 256) {
            if (i < B) out_seqlen[i] = (float)(nc[i + 1] - nc[i]);
            out_off[i] = (float)nc[i];
        }
        return;
    }

    int row = blockIdx.x * 4 + (threadIdx.x >> 6);
    if (row >= total) return;
    int lane = threadIdx.x & 63;

    // seg = searchsorted(nc[1:], row, 'right') == largest j with nc[j] <= row
    int lo = 0, hi = B;
    while (lo < hi) {
        int mid = (lo + hi + 1) >> 1;
        if (nc[mid] <= row) lo = mid; else hi = mid - 1;
    }
    int seg = lo;
    int pos = row - nc[seg];
    // len_a[seg] = diff(so - nc)[seg]
    int len_a = (so[seg + 1] - nc[seg + 1]) - (so[seg] - nc[seg]);
    long src = (long)so[seg] + (long)len_a + (long)pos;

    const float4* __restrict__ vr = (const float4*)(values + src * (long)D);
    float4 a = vr[lane];
    float4 b = vr[lane + 64];

    float ss = a.x * a.x + a.y * a.y + a.z * a.z + a.w * a.w
             + b.x * b.x + b.y * b.y + b.z * b.z + b.w * b.w;

    // 64-lane butterfly reduction
    #pragma unroll
    for (int off = 32; off > 0; off >>= 1)
        ss += __shfl_xor(ss, off, 64);

    float norm  = sqrtf(ss);
    float scale = 1.0f / fmaxf(norm, 1e-6f);

    a.x *= scale; a.y *= scale; a.z *= scale; a.w *= scale;
    b.x *= scale; b.y *= scale; b.z *= scale; b.w *= scale;

    float4* __restrict__ orow = (float4*)(out + (long)row * D);
    orow[lane]      = a;
    orow[lane + 64] = b;
}

extern "C" void kernel_launch(void* const* d_in, const int* in_sizes, int n_in,
                              void* d_out, int out_size, void* d_ws, size_t ws_size,
                              hipStream_t stream) {
    const float* values = (const float*)d_in[0];
    const int*   so     = (const int*)d_in[1];   // seqlen_offsets
    const int*   nc     = (const int*)d_in[2];   // num_candidates_offsets
    // d_in[3] = total_candidates scalar (device); derived host-side instead.

    const int D = 512;
    int B     = in_sizes[1] - 1;                 // 128
    int total = (out_size - (2 * B + 1)) / D;    // 32768

    float* out = (float*)d_out;

    int rowBlocks = (total + 3) / 4;             // 4 rows (waves) per 256-thread block
    hstu_gather_norm_kernel<<<rowBlocks + 1, 256, 0, stream>>>(
        values, so, nc, out, B, total, rowBlocks);
}